// Round 1
// baseline (475.634 us; speedup 1.0000x reference)
//
#include <hip/hip_runtime.h>

#define N_NODES  50000
#define N_EDGES  1600000
#define NODE_DIM 1024
#define HID      128
#define LN_EPS   1e-5f
#define NBUCK    196              // dst>>8 buckets (256 nodes each)
#define SHARD    6250             // N_EDGES / 256

typedef float f32x4 __attribute__((ext_vector_type(4)));
typedef __bf16 bf16x8 __attribute__((ext_vector_type(8)));
typedef unsigned short u16x8 __attribute__((ext_vector_type(8)));

// HW bf16 convert: gfx950 lowers fptrunc f32->bf16 to v_cvt_pk_bf16_f32 (RNE)
__device__ __forceinline__ unsigned short f2bf(float f) {
  __bf16 b = (__bf16)f;
  return __builtin_bit_cast(unsigned short, b);
}
__device__ __forceinline__ unsigned int pkbf(float a, float b) {
  return (unsigned int)f2bf(a) | ((unsigned int)f2bf(b) << 16);
}
__device__ __forceinline__ float bf2f(unsigned short v) {
  return __uint_as_float((unsigned int)v << 16);
}

__device__ __forceinline__ int scan256_excl(int v, int buf[2][256], int t) {
  int cur = 0;
  buf[0][t] = v;
  __syncthreads();
  for (int off = 1; off < 256; off <<= 1) {
    int nxt = cur ^ 1;
    int s = buf[cur][t];
    if (t >= off) s += buf[cur][t - off];
    buf[nxt][t] = s;
    cur = nxt;
    __syncthreads();
  }
  return buf[cur][t] - v;
}

// ---------------------------------------------------------------------------
// K0: one-shot weight convert proj_w f32 -> bf16 (0.5 MB, negligible)
// ---------------------------------------------------------------------------
__global__ __launch_bounds__(256) void k_wcvt(const float* __restrict__ w,
                                              unsigned short* __restrict__ wb) {
  int i = (blockIdx.x * 256 + threadIdx.x) * 4;
  float4 v = *(const float4*)(w + i);
  unsigned int* o = (unsigned int*)(wb + i);
  o[0] = pkbf(v.x, v.y);
  o[1] = pkbf(v.z, v.w);
}

// ---------------------------------------------------------------------------
// K1: h = bf16(relu(x @ proj_w^T + proj_b))
// R1 rework: M-tile 64 (782 blocks, ~3 blocks/CU vs 1.5), register prefetch
// of next K-tile under MFMA, bf16 weights (pre-converted), LDS rows padded
// to 40 shorts (80 B) so bank-quad = (5r+c) mod 8 -> conflict-free.
// ---------------------------------------------------------------------------
#define LDR 40  // padded LDS row stride in shorts

__global__ __launch_bounds__(256) void k_proj(const float* __restrict__ x,
                                              const unsigned short* __restrict__ pwb,
                                              const float* __restrict__ pb,
                                              unsigned short* __restrict__ h) {
  __shared__ unsigned short As[2 * 64 * LDR];   // [sub][row][k32]
  __shared__ unsigned short Bs[2 * 128 * LDR];
  const int tid = threadIdx.x;
  const int m0 = blockIdx.x * 64;
  const int wave = tid >> 6, lane = tid & 63;
  const int wm = (wave >> 1) * 32, wn = (wave & 1) * 64;
  const int fr = lane & 15, ko = (lane >> 4) * 8;

  // A staging: row = tid>>2 (0..63), 16 floats at k-offset (tid&3)*16
  const int arow = tid >> 2, akq = (tid & 3) * 16;
  const int grow = m0 + arow;
  const bool aval = (grow < N_NODES);
  const float* aptr = x + (size_t)grow * NODE_DIM + akq;
  // B staging: row = tid>>1 (0..127), 32 bf16 at k-offset (tid&1)*32
  const int brow = tid >> 1, bkq = (tid & 1) * 32;
  const unsigned short* bptr = pwb + (size_t)brow * NODE_DIM + bkq;

  f32x4 acc[2][4] = {};
  float4 av[4];
  u16x8 bv[4];

  auto LOAD = [&](int k0) {
    if (aval) {
      const float4* p = (const float4*)(aptr + k0);
#pragma unroll
      for (int j = 0; j < 4; j++) av[j] = p[j];
    } else {
#pragma unroll
      for (int j = 0; j < 4; j++) av[j] = make_float4(0.f, 0.f, 0.f, 0.f);
    }
    const u16x8* q = (const u16x8*)(bptr + k0);
#pragma unroll
    for (int j = 0; j < 4; j++) bv[j] = q[j];
  };

  LOAD(0);
  for (int k0 = 0; k0 < NODE_DIM; k0 += 64) {
    __syncthreads();
    // publish A (f32 -> bf16) and B (already bf16) to LDS
    unsigned int* da = (unsigned int*)&As[((akq >> 5) * 64 + arow) * LDR + (akq & 31)];
#pragma unroll
    for (int j = 0; j < 4; j++) {
      da[2 * j]     = pkbf(av[j].x, av[j].y);
      da[2 * j + 1] = pkbf(av[j].z, av[j].w);
    }
    u16x8* db = (u16x8*)&Bs[((bkq >> 5) * 128 + brow) * LDR];
#pragma unroll
    for (int j = 0; j < 4; j++) db[j] = bv[j];
    __syncthreads();

    // prefetch next K-tile while MFMAs run on this one
    if (k0 + 64 < NODE_DIM) LOAD(k0 + 64);

#pragma unroll
    for (int s = 0; s < 2; s++) {
      bf16x8 af[2], bfr[4];
#pragma unroll
      for (int m = 0; m < 2; m++)
        af[m] = *(const bf16x8*)&As[(s * 64 + wm + m * 16 + fr) * LDR + ko];
#pragma unroll
      for (int n = 0; n < 4; n++)
        bfr[n] = *(const bf16x8*)&Bs[(s * 128 + wn + n * 16 + fr) * LDR + ko];
#pragma unroll
      for (int m = 0; m < 2; m++)
#pragma unroll
        for (int n = 0; n < 4; n++)
          acc[m][n] = __builtin_amdgcn_mfma_f32_16x16x32_bf16(af[m], bfr[n], acc[m][n], 0, 0, 0);
    }
  }

  const int cr = (lane >> 4) * 4, cc = lane & 15;
#pragma unroll
  for (int n = 0; n < 4; n++) {
    const int col = wn + n * 16 + cc;
    const float bias = pb[col];
#pragma unroll
    for (int m = 0; m < 2; m++) {
#pragma unroll
      for (int i = 0; i < 4; i++) {
        const int row = m0 + wm + m * 16 + cr + i;
        if (row < N_NODES) {
          float v = acc[m][n][i] + bias;
          h[(size_t)row * HID + col] = f2bf(v > 0.f ? v : 0.f);
        }
      }
    }
  }
}

// ---------------------------------------------------------------------------
// CSR build: hist -> scan -> scan -> scatter(packed) -> per-bucket CSR
// ---------------------------------------------------------------------------
__global__ __launch_bounds__(256) void k_hist(const int* __restrict__ ei,
                                              int* __restrict__ counts) {
  __shared__ int bins[NBUCK];
  int t = threadIdx.x;
  if (t < NBUCK) bins[t] = 0;
  __syncthreads();
  int base = blockIdx.x * SHARD;
  for (int i = t; i < SHARD; i += 256)
    atomicAdd(&bins[ei[N_EDGES + base + i] >> 8], 1);
  __syncthreads();
  if (t < NBUCK) counts[t * 256 + blockIdx.x] = bins[t];
}

__global__ __launch_bounds__(256) void k_s1(const int* __restrict__ counts,
                                            int* __restrict__ basem,
                                            int* __restrict__ btot) {
  __shared__ int buf[2][256];
  int t = threadIdx.x, b = blockIdx.x;
  int v = counts[b * 256 + t];
  int excl = scan256_excl(v, buf, t);
  basem[b * 256 + t] = excl;
  if (t == 255) btot[b] = excl + v;
}

__global__ __launch_bounds__(256) void k_s2(const int* __restrict__ btot,
                                            int* __restrict__ bstart,
                                            float* __restrict__ accum) {
  __shared__ int buf[2][256];
  int t = threadIdx.x;
  int v = (t < NBUCK) ? btot[t] : 0;
  int excl = scan256_excl(v, buf, t);
  if (t < NBUCK) bstart[t] = excl;
  if (t == 0) bstart[NBUCK] = N_EDGES;
  if (t < HID) accum[t] = 0.f;
}

__global__ __launch_bounds__(256) void k_scatter(const int* __restrict__ ei,
                                                 const int* __restrict__ basem,
                                                 const int* __restrict__ bstart,
                                                 unsigned int* __restrict__ bs) {
  __shared__ int cur[NBUCK];
  int t = threadIdx.x;
  if (t < NBUCK) cur[t] = bstart[t] + basem[t * 256 + blockIdx.x];
  __syncthreads();
  int base = blockIdx.x * SHARD;
  for (int i = t; i < SHARD; i += 256) {
    int e = base + i;
    unsigned int src = (unsigned int)ei[e];
    unsigned int dst = (unsigned int)ei[N_EDGES + e];
    int pos = atomicAdd(&cur[dst >> 8], 1);
    bs[pos] = src | ((dst & 255u) << 16);
  }
}

// per-bucket exact CSR (LDS atomics on 1 cursor/edge only); nbr as u16
__global__ __launch_bounds__(256) void k_bucket(const int* __restrict__ bstart,
                                                const unsigned int* __restrict__ bs,
                                                unsigned short* __restrict__ nbr,
                                                int* __restrict__ offs,
                                                int* __restrict__ deg) {
  __shared__ int bins[256];
  __shared__ int buf[2][256];
  __shared__ int curs[256];
  int t = threadIdx.x, b = blockIdx.x;
  int s = bstart[b], e = bstart[b + 1];
  bins[t] = 0;
  __syncthreads();
  for (int i = s + t; i < e; i += 256)
    atomicAdd(&bins[(bs[i] >> 16) & 255u], 1);
  __syncthreads();
  int v = bins[t];
  int excl = scan256_excl(v, buf, t);
  int node = b * 256 + t;
  deg[node]  = v;
  offs[node] = s + excl;
  curs[t]    = s + excl;
  __syncthreads();
  for (int i = s + t; i < e; i += 256) {
    unsigned int p = bs[i];
    int pos = atomicAdd(&curs[(p >> 16) & 255u], 1);
    nbr[pos] = (unsigned short)(p & 0xffffu);
  }
}

// ---------------------------------------------------------------------------
// K_GATHER: mean over neighbors. One wave/node; 4 groups x 16 lanes x 16B;
// 2x unroll -> 8 row-loads in flight per wave.
// ---------------------------------------------------------------------------
__global__ __launch_bounds__(256) void k_gather(const unsigned short* __restrict__ h,
                                                const unsigned short* __restrict__ nbr,
                                                const int* __restrict__ offs,
                                                const int* __restrict__ deg,
                                                unsigned short* __restrict__ mn) {
  const int wave = threadIdx.x >> 6;
  const int lane = threadIdx.x & 63;
  const int node = blockIdx.x * 4 + wave;
  if (node >= N_NODES) return;
  const int g = lane >> 4, li = lane & 15;
  const int d  = deg[node];
  const int st = offs[node];
  float a[8] = {0.f, 0.f, 0.f, 0.f, 0.f, 0.f, 0.f, 0.f};
  int n = g;
  for (; n + 4 < d; n += 8) {
    int s0 = nbr[st + n];
    int s1 = nbr[st + n + 4];
    u16x8 v0 = *(const u16x8*)(h + (size_t)s0 * HID + li * 8);
    u16x8 v1 = *(const u16x8*)(h + (size_t)s1 * HID + li * 8);
#pragma unroll
    for (int k = 0; k < 8; k++) a[k] += bf2f(v0[k]) + bf2f(v1[k]);
  }
  if (n < d) {
    int s0 = nbr[st + n];
    u16x8 v0 = *(const u16x8*)(h + (size_t)s0 * HID + li * 8);
#pragma unroll
    for (int k = 0; k < 8; k++) a[k] += bf2f(v0[k]);
  }
#pragma unroll
  for (int k = 0; k < 8; k++) {
    a[k] += __shfl_xor(a[k], 16);
    a[k] += __shfl_xor(a[k], 32);
  }
  if (g == 0) {
    float inv = 1.f / fmaxf((float)d, 1.f);
    u16x8 r;
#pragma unroll
    for (int k = 0; k < 8; k++) r[k] = f2bf(a[k] * inv);
    *(u16x8*)(mn + (size_t)node * HID + li * 8) = r;
  }
}

// ---------------------------------------------------------------------------
// K_SAGE: h2 = [mn|h] @ [wl|wr]^T + lb, fused LayerNorm+ReLU+mean-pool.
// h2 never hits global memory (validated in R3).
// ---------------------------------------------------------------------------
__global__ __launch_bounds__(256) void k_sage(const unsigned short* __restrict__ mn,
                                              const unsigned short* __restrict__ h,
                                              const float* __restrict__ wl,
                                              const float* __restrict__ wr,
                                              const float* __restrict__ lb,
                                              const float* __restrict__ lg,
                                              const float* __restrict__ lbt,
                                              float* __restrict__ accum) {
  __shared__ unsigned short As[128 * 32];
  __shared__ unsigned short Bs[128 * 32];
  __shared__ float T3[32 * 128];
  __shared__ float red[4][128];
  const int tid = threadIdx.x;
  const int m0 = blockIdx.x * 128;
  const int wave = tid >> 6, lane = tid & 63;
  const int wm = (wave >> 1) * 64, wn = (wave & 1) * 64;
  const int srow = tid >> 1, scol = (tid & 1) * 16;
  const int fr = lane & 15, ko = (lane >> 4) * 8;

  f32x4 acc[4][4] = {};

  for (int k0 = 0; k0 < 2 * HID; k0 += 32) {
    const unsigned short* baseA = (k0 < HID) ? mn : h;
    const float* baseB = (k0 < HID) ? wl : wr;
    const int kk = (k0 & (HID - 1)) + scol;
    const int arow = m0 + srow;
    u16x8 a0 = {0, 0, 0, 0, 0, 0, 0, 0}, a1 = a0;
    if (arow < N_NODES) {
      const u16x8* p = (const u16x8*)(baseA + (size_t)arow * HID + kk);
      a0 = p[0]; a1 = p[1];
    }
    const float4* q = (const float4*)(baseB + (size_t)srow * HID + kk);
    float4 b0 = q[0], b1 = q[1], b2 = q[2], b3 = q[3];

    __syncthreads();
    *(u16x8*)&As[srow * 32 + scol]     = a0;
    *(u16x8*)&As[srow * 32 + scol + 8] = a1;
    unsigned int* db = (unsigned int*)&Bs[srow * 32 + scol];
    db[0] = pkbf(b0.x, b0.y); db[1] = pkbf(b0.z, b0.w);
    db[2] = pkbf(b1.x, b1.y); db[3] = pkbf(b1.z, b1.w);
    db[4] = pkbf(b2.x, b2.y); db[5] = pkbf(b2.z, b2.w);
    db[6] = pkbf(b3.x, b3.y); db[7] = pkbf(b3.z, b3.w);
    __syncthreads();

    bf16x8 af[4], bfr[4];
#pragma unroll
    for (int m = 0; m < 4; m++)
      af[m] = *(const bf16x8*)&As[(wm + m * 16 + fr) * 32 + ko];
#pragma unroll
    for (int n = 0; n < 4; n++)
      bfr[n] = *(const bf16x8*)&Bs[(wn + n * 16 + fr) * 32 + ko];
#pragma unroll
    for (int m = 0; m < 4; m++)
#pragma unroll
      for (int n = 0; n < 4; n++)
        acc[m][n] = __builtin_amdgcn_mfma_f32_16x16x32_bf16(af[m], bfr[n], acc[m][n], 0, 0, 0);
  }

  const int cr = (lane >> 4) * 4, cc = lane & 15;
  const int p = wave >> 1;
  const float g0 = lg[lane], g1 = lg[lane + 64];
  const float t0 = lbt[lane], t1 = lbt[lane + 64];
  float ax = 0.f, ay = 0.f;
#pragma unroll
  for (int m = 0; m < 4; m++) {
    __syncthreads();
#pragma unroll
    for (int n = 0; n < 4; n++) {
      const int col = wn + n * 16 + cc;
      const float bias = lb[col];
#pragma unroll
      for (int i = 0; i < 4; i++)
        T3[(p * 16 + cr + i) * 128 + col] = acc[m][n][i] + bias;
    }
    __syncthreads();
    for (int r8 = 0; r8 < 8; r8++) {
      int q8 = wave * 8 + r8;
      int grow = m0 + (q8 >> 4) * 64 + m * 16 + (q8 & 15);
      float v0 = T3[q8 * 128 + lane];
      float v1 = T3[q8 * 128 + lane + 64];
      float sum = v0 + v1, ss = v0 * v0 + v1 * v1;
#pragma unroll
      for (int off = 32; off > 0; off >>= 1) {
        sum += __shfl_xor(sum, off);
        ss  += __shfl_xor(ss, off);
      }
      float mu  = sum * (1.f / HID);
      float var = ss * (1.f / HID) - mu * mu;
      float rinv = rsqrtf(var + LN_EPS);
      if (grow < N_NODES) {
        float y0 = (v0 - mu) * rinv * g0 + t0;
        float y1 = (v1 - mu) * rinv * g1 + t1;
        ax += fmaxf(y0, 0.f);
        ay += fmaxf(y1, 0.f);
      }
    }
  }
  red[wave][lane]      = ax;
  red[wave][lane + 64] = ay;
  __syncthreads();
  if (wave == 0) {
    float a  = red[0][lane] + red[1][lane] + red[2][lane] + red[3][lane];
    float bb = red[0][lane + 64] + red[1][lane + 64] + red[2][lane + 64] + red[3][lane + 64];
    atomicAdd(&accum[lane], a);
    atomicAdd(&accum[lane + 64], bb);
  }
}

// ---------------------------------------------------------------------------
__global__ __launch_bounds__(128) void k_final(const float* __restrict__ accum,
                                               const float* __restrict__ ow,
                                               const float* __restrict__ ob,
                                               float* __restrict__ out) {
  __shared__ float gs[HID];
  int t = threadIdx.x;
  gs[t] = accum[t] * (1.f / N_NODES);
  __syncthreads();
  float s = ob[t];
  for (int k = 0; k < HID; k++) s += gs[k] * ow[t * HID + k];
  out[t] = s;
}

// ---------------------------------------------------------------------------
extern "C" void kernel_launch(void* const* d_in, const int* in_sizes, int n_in,
                              void* d_out, int out_size, void* d_ws, size_t ws_size,
                              hipStream_t stream) {
  const float* x   = (const float*)d_in[0];
  const int*   ei  = (const int*)d_in[1];
  const float* pw  = (const float*)d_in[2];
  const float* pb  = (const float*)d_in[3];
  const float* wl  = (const float*)d_in[4];
  const float* lb  = (const float*)d_in[5];
  const float* wr  = (const float*)d_in[6];
  const float* lg  = (const float*)d_in[7];
  const float* lbt = (const float*)d_in[8];
  const float* ow  = (const float*)d_in[9];
  const float* ob  = (const float*)d_in[10];
  float* out = (float*)d_out;

  const int PAD = NBUCK * 256;  // 50176
  unsigned short* h  = (unsigned short*)d_ws;                   // PAD*128 bf16
  unsigned short* mn = h + (size_t)PAD * HID;                   // PAD*128 bf16
  unsigned int* bsp  = (unsigned int*)(mn + (size_t)PAD * HID); // E packed u32
  unsigned short* nbr = (unsigned short*)(bsp + N_EDGES);       // E u16
  int* counts = (int*)(nbr + N_EDGES);                          // NBUCK*256
  int* basem  = counts + NBUCK * 256;
  int* btot   = basem + NBUCK * 256;                            // 256
  int* bstart = btot + 256;                                     // 256
  int* offs   = bstart + 256;                                   // PAD
  int* deg    = offs + PAD;                                     // PAD
  float* accum = (float*)(deg + PAD);                           // 128
  unsigned short* pwb = (unsigned short*)(accum + 128);         // HID*NODE_DIM bf16

  const int MB  = (N_NODES + 127) / 128;  // 391 (k_sage)
  const int MB2 = (N_NODES + 63) / 64;    // 782 (k_proj)

  hipLaunchKernelGGL(k_wcvt,    dim3(HID * NODE_DIM / 1024), dim3(256), 0, stream, pw, pwb);
  hipLaunchKernelGGL(k_proj,    dim3(MB2),   dim3(256), 0, stream, x, pwb, pb, h);
  hipLaunchKernelGGL(k_hist,    dim3(256),   dim3(256), 0, stream, ei, counts);
  hipLaunchKernelGGL(k_s1,      dim3(NBUCK), dim3(256), 0, stream, counts, basem, btot);
  hipLaunchKernelGGL(k_s2,      dim3(1),     dim3(256), 0, stream, btot, bstart, accum);
  hipLaunchKernelGGL(k_scatter, dim3(256),   dim3(256), 0, stream, ei, basem, bstart, bsp);
  hipLaunchKernelGGL(k_bucket,  dim3(NBUCK), dim3(256), 0, stream, bstart, bsp, nbr, offs, deg);
  hipLaunchKernelGGL(k_gather,  dim3((N_NODES + 3) / 4), dim3(256), 0, stream, h, nbr, offs, deg, mn);
  hipLaunchKernelGGL(k_sage,    dim3(MB),    dim3(256), 0, stream, mn, h, wl, wr, lb, lg, lbt, accum);
  hipLaunchKernelGGL(k_final,   dim3(1),     dim3(128), 0, stream, accum, ow, ob, out);
}

// Round 2
// 470.898 us; speedup vs baseline: 1.0101x; 1.0101x over previous
//
#include <hip/hip_runtime.h>

#define N_NODES  50000
#define N_EDGES  1600000
#define NODE_DIM 1024
#define HID      128
#define LN_EPS   1e-5f
#define NBUCK    196              // dst>>8 buckets (256 nodes each)
#define SHARD    6250             // N_EDGES / 256

typedef float f32x4 __attribute__((ext_vector_type(4)));
typedef __bf16 bf16x8 __attribute__((ext_vector_type(8)));
typedef unsigned short u16x8 __attribute__((ext_vector_type(8)));

// HW bf16 convert: gfx950 lowers fptrunc f32->bf16 to v_cvt_pk_bf16_f32 (RNE)
__device__ __forceinline__ unsigned short f2bf(float f) {
  __bf16 b = (__bf16)f;
  return __builtin_bit_cast(unsigned short, b);
}
__device__ __forceinline__ unsigned int pkbf(float a, float b) {
  return (unsigned int)f2bf(a) | ((unsigned int)f2bf(b) << 16);
}
__device__ __forceinline__ float bf2f(unsigned short v) {
  return __uint_as_float((unsigned int)v << 16);
}

__device__ __forceinline__ int scan256_excl(int v, int buf[2][256], int t) {
  int cur = 0;
  buf[0][t] = v;
  __syncthreads();
  for (int off = 1; off < 256; off <<= 1) {
    int nxt = cur ^ 1;
    int s = buf[cur][t];
    if (t >= off) s += buf[cur][t - off];
    buf[nxt][t] = s;
    cur = nxt;
    __syncthreads();
  }
  return buf[cur][t] - v;
}

// ---------------------------------------------------------------------------
// K0: one-shot weight convert proj_w f32 -> bf16 (0.5 MB, negligible)
// ---------------------------------------------------------------------------
__global__ __launch_bounds__(256) void k_wcvt(const float* __restrict__ w,
                                              unsigned short* __restrict__ wb) {
  int i = (blockIdx.x * 256 + threadIdx.x) * 4;
  float4 v = *(const float4*)(w + i);
  unsigned int* o = (unsigned int*)(wb + i);
  o[0] = pkbf(v.x, v.y);
  o[1] = pkbf(v.z, v.w);
}

// ---------------------------------------------------------------------------
// K1: h = bf16(relu(x @ proj_w^T + proj_b))
// R2: DRAM-granularity rework. Every staging wave-instruction now covers
// whole 128B cache lines: lane L reads byte (L&31)*16 of row (L>>5) ->
// one instr = 2 full rows x 512 B contiguous (A), 4 rows x 256 B (B).
// K-step 128, M-tile 64, LDS 48 KB (3 blocks/CU), XOR-swizzled LDS
// (byte ^= (row&7)<<4) instead of padding -> frag ds_read_b128 <=2-way.
// ---------------------------------------------------------------------------
__global__ __launch_bounds__(256, 3) void k_proj(const float* __restrict__ x,
                                                 const unsigned short* __restrict__ pwb,
                                                 const float* __restrict__ pb,
                                                 unsigned short* __restrict__ h) {
  __shared__ unsigned short As[64 * 128];    // [row][k] bf16, 256 B/row, swizzled
  __shared__ unsigned short Bs[128 * 128];   // [row][k] bf16, 256 B/row, swizzled
  const int tid = threadIdx.x;
  const int m0 = blockIdx.x * 64;
  const int wave = tid >> 6, lane = tid & 63;
  const int wm = (wave >> 1) * 32, wn = (wave & 1) * 64;
  const int fr = lane & 15;

  // A staging: per instr j, wave covers rows w*16+j*2+(lane>>5), bytes (lane&31)*16
  const int arL = wave * 16 + (lane >> 5);    // + j*2
  const int acF = (lane & 31) * 4;            // f32 column
  // B staging: per instr j, wave covers rows w*32+j*4+(lane>>4), bytes (lane&15)*16
  const int brL = wave * 32 + (lane >> 4);    // + j*4
  const int bcE = (lane & 15) * 8;            // bf16 column

  f32x4 acc[2][4] = {};
  float4 av[8];
  u16x8 bv[8];

  auto LOAD = [&](int k0) {
#pragma unroll
    for (int j = 0; j < 8; j++) {
      const int r = arL + j * 2;
      const int grow = m0 + r;
      if (grow < N_NODES)
        av[j] = *(const float4*)(x + (size_t)grow * NODE_DIM + k0 + acF);
      else
        av[j] = make_float4(0.f, 0.f, 0.f, 0.f);
    }
#pragma unroll
    for (int j = 0; j < 8; j++) {
      const int r = brL + j * 4;
      bv[j] = *(const u16x8*)(pwb + (size_t)r * NODE_DIM + k0 + bcE);
    }
  };

  LOAD(0);
  for (int k0 = 0; k0 < NODE_DIM; k0 += 128) {
    __syncthreads();   // prev MFMA phase done with LDS
    // publish A: f32->bf16, 8 B per j, XOR-swizzled
#pragma unroll
    for (int j = 0; j < 8; j++) {
      const int r = arL + j * 2;
      const int off = r * 256 + (((lane & 31) * 8) ^ ((r & 7) << 4));
      unsigned int lo = pkbf(av[j].x, av[j].y);
      unsigned int hi = pkbf(av[j].z, av[j].w);
      *(uint2*)((char*)As + off) = make_uint2(lo, hi);
    }
    // publish B: straight 16 B copy, XOR-swizzled
#pragma unroll
    for (int j = 0; j < 8; j++) {
      const int r = brL + j * 4;
      const int off = r * 256 + (((lane & 15) * 16) ^ ((r & 7) << 4));
      *(u16x8*)((char*)Bs + off) = bv[j];
    }
    __syncthreads();

    if (k0 + 128 < NODE_DIM) LOAD(k0 + 128);  // prefetch under MFMA

#pragma unroll
    for (int s = 0; s < 4; s++) {
      const int kb = s * 64 + (lane >> 4) * 16;  // byte-in-row of fragment
      bf16x8 af[2], bfr[4];
#pragma unroll
      for (int m = 0; m < 2; m++) {
        const int r = wm + m * 16 + fr;
        af[m] = *(const bf16x8*)((char*)As + r * 256 + (kb ^ ((r & 7) << 4)));
      }
#pragma unroll
      for (int n = 0; n < 4; n++) {
        const int r = wn + n * 16 + fr;
        bfr[n] = *(const bf16x8*)((char*)Bs + r * 256 + (kb ^ ((r & 7) << 4)));
      }
#pragma unroll
      for (int m = 0; m < 2; m++)
#pragma unroll
        for (int n = 0; n < 4; n++)
          acc[m][n] = __builtin_amdgcn_mfma_f32_16x16x32_bf16(af[m], bfr[n], acc[m][n], 0, 0, 0);
    }
  }

  const int cr = (lane >> 4) * 4, cc = lane & 15;
#pragma unroll
  for (int n = 0; n < 4; n++) {
    const int col = wn + n * 16 + cc;
    const float bias = pb[col];
#pragma unroll
    for (int m = 0; m < 2; m++) {
#pragma unroll
      for (int i = 0; i < 4; i++) {
        const int row = m0 + wm + m * 16 + cr + i;
        if (row < N_NODES) {
          float v = acc[m][n][i] + bias;
          h[(size_t)row * HID + col] = f2bf(v > 0.f ? v : 0.f);
        }
      }
    }
  }
}

// ---------------------------------------------------------------------------
// CSR build: hist -> scan -> scan -> scatter(packed) -> per-bucket CSR
// ---------------------------------------------------------------------------
__global__ __launch_bounds__(256) void k_hist(const int* __restrict__ ei,
                                              int* __restrict__ counts) {
  __shared__ int bins[NBUCK];
  int t = threadIdx.x;
  if (t < NBUCK) bins[t] = 0;
  __syncthreads();
  int base = blockIdx.x * SHARD;
  for (int i = t; i < SHARD; i += 256)
    atomicAdd(&bins[ei[N_EDGES + base + i] >> 8], 1);
  __syncthreads();
  if (t < NBUCK) counts[t * 256 + blockIdx.x] = bins[t];
}

__global__ __launch_bounds__(256) void k_s1(const int* __restrict__ counts,
                                            int* __restrict__ basem,
                                            int* __restrict__ btot) {
  __shared__ int buf[2][256];
  int t = threadIdx.x, b = blockIdx.x;
  int v = counts[b * 256 + t];
  int excl = scan256_excl(v, buf, t);
  basem[b * 256 + t] = excl;
  if (t == 255) btot[b] = excl + v;
}

__global__ __launch_bounds__(256) void k_s2(const int* __restrict__ btot,
                                            int* __restrict__ bstart,
                                            float* __restrict__ accum) {
  __shared__ int buf[2][256];
  int t = threadIdx.x;
  int v = (t < NBUCK) ? btot[t] : 0;
  int excl = scan256_excl(v, buf, t);
  if (t < NBUCK) bstart[t] = excl;
  if (t == 0) bstart[NBUCK] = N_EDGES;
  if (t < HID) accum[t] = 0.f;
}

__global__ __launch_bounds__(256) void k_scatter(const int* __restrict__ ei,
                                                 const int* __restrict__ basem,
                                                 const int* __restrict__ bstart,
                                                 unsigned int* __restrict__ bs) {
  __shared__ int cur[NBUCK];
  int t = threadIdx.x;
  if (t < NBUCK) cur[t] = bstart[t] + basem[t * 256 + blockIdx.x];
  __syncthreads();
  int base = blockIdx.x * SHARD;
  for (int i = t; i < SHARD; i += 256) {
    int e = base + i;
    unsigned int src = (unsigned int)ei[e];
    unsigned int dst = (unsigned int)ei[N_EDGES + e];
    int pos = atomicAdd(&cur[dst >> 8], 1);
    bs[pos] = src | ((dst & 255u) << 16);
  }
}

// per-bucket exact CSR (LDS atomics on 1 cursor/edge only); nbr as u16
__global__ __launch_bounds__(256) void k_bucket(const int* __restrict__ bstart,
                                                const unsigned int* __restrict__ bs,
                                                unsigned short* __restrict__ nbr,
                                                int* __restrict__ offs,
                                                int* __restrict__ deg) {
  __shared__ int bins[256];
  __shared__ int buf[2][256];
  __shared__ int curs[256];
  int t = threadIdx.x, b = blockIdx.x;
  int s = bstart[b], e = bstart[b + 1];
  bins[t] = 0;
  __syncthreads();
  for (int i = s + t; i < e; i += 256)
    atomicAdd(&bins[(bs[i] >> 16) & 255u], 1);
  __syncthreads();
  int v = bins[t];
  int excl = scan256_excl(v, buf, t);
  int node = b * 256 + t;
  deg[node]  = v;
  offs[node] = s + excl;
  curs[t]    = s + excl;
  __syncthreads();
  for (int i = s + t; i < e; i += 256) {
    unsigned int p = bs[i];
    int pos = atomicAdd(&curs[(p >> 16) & 255u], 1);
    nbr[pos] = (unsigned short)(p & 0xffffu);
  }
}

// ---------------------------------------------------------------------------
// K_GATHER: mean over neighbors. One wave/node; 4 groups x 16 lanes x 16B;
// 2x unroll -> 8 row-loads in flight per wave.
// ---------------------------------------------------------------------------
__global__ __launch_bounds__(256) void k_gather(const unsigned short* __restrict__ h,
                                                const unsigned short* __restrict__ nbr,
                                                const int* __restrict__ offs,
                                                const int* __restrict__ deg,
                                                unsigned short* __restrict__ mn) {
  const int wave = threadIdx.x >> 6;
  const int lane = threadIdx.x & 63;
  const int node = blockIdx.x * 4 + wave;
  if (node >= N_NODES) return;
  const int g = lane >> 4, li = lane & 15;
  const int d  = deg[node];
  const int st = offs[node];
  float a[8] = {0.f, 0.f, 0.f, 0.f, 0.f, 0.f, 0.f, 0.f};
  int n = g;
  for (; n + 4 < d; n += 8) {
    int s0 = nbr[st + n];
    int s1 = nbr[st + n + 4];
    u16x8 v0 = *(const u16x8*)(h + (size_t)s0 * HID + li * 8);
    u16x8 v1 = *(const u16x8*)(h + (size_t)s1 * HID + li * 8);
#pragma unroll
    for (int k = 0; k < 8; k++) a[k] += bf2f(v0[k]) + bf2f(v1[k]);
  }
  if (n < d) {
    int s0 = nbr[st + n];
    u16x8 v0 = *(const u16x8*)(h + (size_t)s0 * HID + li * 8);
#pragma unroll
    for (int k = 0; k < 8; k++) a[k] += bf2f(v0[k]);
  }
#pragma unroll
  for (int k = 0; k < 8; k++) {
    a[k] += __shfl_xor(a[k], 16);
    a[k] += __shfl_xor(a[k], 32);
  }
  if (g == 0) {
    float inv = 1.f / fmaxf((float)d, 1.f);
    u16x8 r;
#pragma unroll
    for (int k = 0; k < 8; k++) r[k] = f2bf(a[k] * inv);
    *(u16x8*)(mn + (size_t)node * HID + li * 8) = r;
  }
}

// ---------------------------------------------------------------------------
// K_SAGE: h2 = [mn|h] @ [wl|wr]^T + lb, fused LayerNorm+ReLU+mean-pool.
// h2 never hits global memory (validated in R3).
// ---------------------------------------------------------------------------
__global__ __launch_bounds__(256) void k_sage(const unsigned short* __restrict__ mn,
                                              const unsigned short* __restrict__ h,
                                              const float* __restrict__ wl,
                                              const float* __restrict__ wr,
                                              const float* __restrict__ lb,
                                              const float* __restrict__ lg,
                                              const float* __restrict__ lbt,
                                              float* __restrict__ accum) {
  __shared__ unsigned short As[128 * 32];
  __shared__ unsigned short Bs[128 * 32];
  __shared__ float T3[32 * 128];
  __shared__ float red[4][128];
  const int tid = threadIdx.x;
  const int m0 = blockIdx.x * 128;
  const int wave = tid >> 6, lane = tid & 63;
  const int wm = (wave >> 1) * 64, wn = (wave & 1) * 64;
  const int srow = tid >> 1, scol = (tid & 1) * 16;
  const int fr = lane & 15, ko = (lane >> 4) * 8;

  f32x4 acc[4][4] = {};

  for (int k0 = 0; k0 < 2 * HID; k0 += 32) {
    const unsigned short* baseA = (k0 < HID) ? mn : h;
    const float* baseB = (k0 < HID) ? wl : wr;
    const int kk = (k0 & (HID - 1)) + scol;
    const int arow = m0 + srow;
    u16x8 a0 = {0, 0, 0, 0, 0, 0, 0, 0}, a1 = a0;
    if (arow < N_NODES) {
      const u16x8* p = (const u16x8*)(baseA + (size_t)arow * HID + kk);
      a0 = p[0]; a1 = p[1];
    }
    const float4* q = (const float4*)(baseB + (size_t)srow * HID + kk);
    float4 b0 = q[0], b1 = q[1], b2 = q[2], b3 = q[3];

    __syncthreads();
    *(u16x8*)&As[srow * 32 + scol]     = a0;
    *(u16x8*)&As[srow * 32 + scol + 8] = a1;
    unsigned int* db = (unsigned int*)&Bs[srow * 32 + scol];
    db[0] = pkbf(b0.x, b0.y); db[1] = pkbf(b0.z, b0.w);
    db[2] = pkbf(b1.x, b1.y); db[3] = pkbf(b1.z, b1.w);
    db[4] = pkbf(b2.x, b2.y); db[5] = pkbf(b2.z, b2.w);
    db[6] = pkbf(b3.x, b3.y); db[7] = pkbf(b3.z, b3.w);
    __syncthreads();

    bf16x8 af[4], bfr[4];
#pragma unroll
    for (int m = 0; m < 4; m++)
      af[m] = *(const bf16x8*)&As[(wm + m * 16 + fr) * 32 + ko];
#pragma unroll
    for (int n = 0; n < 4; n++)
      bfr[n] = *(const bf16x8*)&Bs[(wn + n * 16 + fr) * 32 + ko];
#pragma unroll
    for (int m = 0; m < 4; m++)
#pragma unroll
      for (int n = 0; n < 4; n++)
        acc[m][n] = __builtin_amdgcn_mfma_f32_16x16x32_bf16(af[m], bfr[n], acc[m][n], 0, 0, 0);
  }

  const int cr = (lane >> 4) * 4, cc = lane & 15;
  const int p = wave >> 1;
  const float g0 = lg[lane], g1 = lg[lane + 64];
  const float t0 = lbt[lane], t1 = lbt[lane + 64];
  float ax = 0.f, ay = 0.f;
#pragma unroll
  for (int m = 0; m < 4; m++) {
    __syncthreads();
#pragma unroll
    for (int n = 0; n < 4; n++) {
      const int col = wn + n * 16 + cc;
      const float bias = lb[col];
#pragma unroll
      for (int i = 0; i < 4; i++)
        T3[(p * 16 + cr + i) * 128 + col] = acc[m][n][i] + bias;
    }
    __syncthreads();
    for (int r8 = 0; r8 < 8; r8++) {
      int q8 = wave * 8 + r8;
      int grow = m0 + (q8 >> 4) * 64 + m * 16 + (q8 & 15);
      float v0 = T3[q8 * 128 + lane];
      float v1 = T3[q8 * 128 + lane + 64];
      float sum = v0 + v1, ss = v0 * v0 + v1 * v1;
#pragma unroll
      for (int off = 32; off > 0; off >>= 1) {
        sum += __shfl_xor(sum, off);
        ss  += __shfl_xor(ss, off);
      }
      float mu  = sum * (1.f / HID);
      float var = ss * (1.f / HID) - mu * mu;
      float rinv = rsqrtf(var + LN_EPS);
      if (grow < N_NODES) {
        float y0 = (v0 - mu) * rinv * g0 + t0;
        float y1 = (v1 - mu) * rinv * g1 + t1;
        ax += fmaxf(y0, 0.f);
        ay += fmaxf(y1, 0.f);
      }
    }
  }
  red[wave][lane]      = ax;
  red[wave][lane + 64] = ay;
  __syncthreads();
  if (wave == 0) {
    float a  = red[0][lane] + red[1][lane] + red[2][lane] + red[3][lane];
    float bb = red[0][lane + 64] + red[1][lane + 64] + red[2][lane + 64] + red[3][lane + 64];
    atomicAdd(&accum[lane], a);
    atomicAdd(&accum[lane + 64], bb);
  }
}

// ---------------------------------------------------------------------------
__global__ __launch_bounds__(128) void k_final(const float* __restrict__ accum,
                                               const float* __restrict__ ow,
                                               const float* __restrict__ ob,
                                               float* __restrict__ out) {
  __shared__ float gs[HID];
  int t = threadIdx.x;
  gs[t] = accum[t] * (1.f / N_NODES);
  __syncthreads();
  float s = ob[t];
  for (int k = 0; k < HID; k++) s += gs[k] * ow[t * HID + k];
  out[t] = s;
}

// ---------------------------------------------------------------------------
extern "C" void kernel_launch(void* const* d_in, const int* in_sizes, int n_in,
                              void* d_out, int out_size, void* d_ws, size_t ws_size,
                              hipStream_t stream) {
  const float* x   = (const float*)d_in[0];
  const int*   ei  = (const int*)d_in[1];
  const float* pw  = (const float*)d_in[2];
  const float* pb  = (const float*)d_in[3];
  const float* wl  = (const float*)d_in[4];
  const float* lb  = (const float*)d_in[5];
  const float* wr  = (const float*)d_in[6];
  const float* lg  = (const float*)d_in[7];
  const float* lbt = (const float*)d_in[8];
  const float* ow  = (const float*)d_in[9];
  const float* ob  = (const float*)d_in[10];
  float* out = (float*)d_out;

  const int PAD = NBUCK * 256;  // 50176
  unsigned short* h  = (unsigned short*)d_ws;                   // PAD*128 bf16
  unsigned short* mn = h + (size_t)PAD * HID;                   // PAD*128 bf16
  unsigned int* bsp  = (unsigned int*)(mn + (size_t)PAD * HID); // E packed u32
  unsigned short* nbr = (unsigned short*)(bsp + N_EDGES);       // E u16
  int* counts = (int*)(nbr + N_EDGES);                          // NBUCK*256
  int* basem  = counts + NBUCK * 256;
  int* btot   = basem + NBUCK * 256;                            // 256
  int* bstart = btot + 256;                                     // 256
  int* offs   = bstart + 256;                                   // PAD
  int* deg    = offs + PAD;                                     // PAD
  float* accum = (float*)(deg + PAD);                           // 128
  unsigned short* pwb = (unsigned short*)(accum + 128);         // HID*NODE_DIM bf16

  const int MB  = (N_NODES + 127) / 128;  // 391 (k_sage)
  const int MB2 = (N_NODES + 63) / 64;    // 782 (k_proj)

  hipLaunchKernelGGL(k_wcvt,    dim3(HID * NODE_DIM / 1024), dim3(256), 0, stream, pw, pwb);
  hipLaunchKernelGGL(k_proj,    dim3(MB2),   dim3(256), 0, stream, x, pwb, pb, h);
  hipLaunchKernelGGL(k_hist,    dim3(256),   dim3(256), 0, stream, ei, counts);
  hipLaunchKernelGGL(k_s1,      dim3(NBUCK), dim3(256), 0, stream, counts, basem, btot);
  hipLaunchKernelGGL(k_s2,      dim3(1),     dim3(256), 0, stream, btot, bstart, accum);
  hipLaunchKernelGGL(k_scatter, dim3(256),   dim3(256), 0, stream, ei, basem, bstart, bsp);
  hipLaunchKernelGGL(k_bucket,  dim3(NBUCK), dim3(256), 0, stream, bstart, bsp, nbr, offs, deg);
  hipLaunchKernelGGL(k_gather,  dim3((N_NODES + 3) / 4), dim3(256), 0, stream, h, nbr, offs, deg, mn);
  hipLaunchKernelGGL(k_sage,    dim3(MB),    dim3(256), 0, stream, mn, h, wl, wr, lb, lg, lbt, accum);
  hipLaunchKernelGGL(k_final,   dim3(1),     dim3(128), 0, stream, accum, ow, ob, out);
}